// Round 1
// baseline (161.246 us; speedup 1.0000x reference)
//
#include <hip/hip_runtime.h>
#include <stdint.h>
#include <math.h>

typedef __attribute__((ext_vector_type(8))) short short8;
typedef __attribute__((ext_vector_type(4))) float f32x4;

#define T_SEQ 2048
#define MROWS 4096

// ws byte offsets
#define OFF_XBF   ((size_t)0)          // 4096x1024 bf16 : 8 MB
#define OFF_WQ    ((size_t)8388608)    // 1024x1024 bf16 : 2 MB
#define OFF_WK    ((size_t)10485760)
#define OFF_WV    ((size_t)12582912)
#define OFF_WO    ((size_t)14680064)
#define OFF_Q     ((size_t)16777216)   // 4096x1024 bf16 (roped, *0.125)
#define OFF_K     ((size_t)25165824)   // 4096x1024 bf16 (roped)
#define OFF_VT    ((size_t)33554432)   // [b][e][t] 2x1024x2048 bf16
#define OFF_ATT   ((size_t)41943040)   // 4096x1024 bf16
#define OFF_COS   ((size_t)50331648)   // 2048x32 f32
#define OFF_SIN   ((size_t)50593792)   // 2048x32 f32

__device__ __forceinline__ unsigned short f2bf(float f) {
  unsigned u = __float_as_uint(f);
  u += 0x7fffu + ((u >> 16) & 1u);
  return (unsigned short)(u >> 16);
}

__device__ __forceinline__ void gld_lds16(const void* g, void* l) {
  __builtin_amdgcn_global_load_lds(
      (__attribute__((address_space(1))) void*)(g),
      (__attribute__((address_space(3))) void*)(l), 16, 0, 0);
}

// ---------------- prep: bf16 conversions + rope tables ----------------
__global__ void prep_kernel(const float* x, const float* wq, const float* wk,
                            const float* wv, const float* wo, char* ws) {
  const size_t NX = (size_t)MROWS * 1024;   // 4194304
  const size_t NW = (size_t)1024 * 1024;    // 1048576
  const size_t NT = (size_t)T_SEQ * 32;     // 65536
  unsigned short* xb = (unsigned short*)(ws + OFF_XBF);
  unsigned short* qb = (unsigned short*)(ws + OFF_WQ);
  unsigned short* kb = (unsigned short*)(ws + OFF_WK);
  unsigned short* vb = (unsigned short*)(ws + OFF_WV);
  unsigned short* ob = (unsigned short*)(ws + OFF_WO);
  float* cosb = (float*)(ws + OFF_COS);
  float* sinb = (float*)(ws + OFF_SIN);
  size_t total = NX + 4 * NW + NT;
  for (size_t i = (size_t)blockIdx.x * blockDim.x + threadIdx.x; i < total;
       i += (size_t)gridDim.x * blockDim.x) {
    if (i < NX) {
      xb[i] = f2bf(x[i]);
    } else if (i < NX + NW) {
      qb[i - NX] = f2bf(wq[i - NX]);
    } else if (i < NX + 2 * NW) {
      kb[i - NX - NW] = f2bf(wk[i - NX - NW]);
    } else if (i < NX + 3 * NW) {
      vb[i - NX - 2 * NW] = f2bf(wv[i - NX - 2 * NW]);
    } else if (i < NX + 4 * NW) {
      ob[i - NX - 3 * NW] = f2bf(wo[i - NX - 3 * NW]);
    } else {
      size_t j = i - NX - 4 * NW;
      int t = (int)(j >> 5), ii = (int)(j & 31);
      double th = exp(-(double)ii * (9.210340371976184 / 32.0));
      float ang = (float)t * (float)th;
      cosb[j] = cosf(ang);
      sinb[j] = sinf(ang);
    }
  }
}

// ---------------- GEMM: C = A(MxK) @ W(NxK)^T, bf16 in, modes out ------
// MODE 0: rope epilogue, *qscale, bf16 [row][col]
// MODE 1: bf16 transposed store V^T[b][e][t]
// MODE 2: f32 [row][col]
template <int MODE>
__global__ __launch_bounds__(256, 2) void gemm_bt(
    const unsigned short* Abf, const unsigned short* Wbf, void* out,
    const float* cosT, const float* sinT, float qscale) {
  const int K = 1024, N = 1024;
  int bid = blockIdx.x;
  int bm = bid >> 3, bn = bid & 7;  // N/128 = 8
  int tid = threadIdx.x;
  int l = tid & 63, w = tid >> 6;
  int wm = w >> 1, wn = w & 1;
  int g = l >> 4;

  __shared__ __align__(16) char ldsbuf[32768];  // [buf][A 8K | B 8K]

  auto stage = [&](int kt, int buf) {
    int base = buf * 16384;
#pragma unroll
    for (int i = 0; i < 2; ++i) {
      int p = (w * 2 + i) * 1024;
      int row = ((p >> 6)) + (l >> 2);
      int u = l & 3;
      const char* ga = (const char*)Abf +
          ((size_t)(bm * 128 + row) * K + (size_t)kt * 32) * 2 + u * 16;
      gld_lds16(ga, ldsbuf + base + p);
      const char* gb = (const char*)Wbf +
          ((size_t)(bn * 128 + row) * K + (size_t)kt * 32) * 2 + u * 16;
      gld_lds16(gb, ldsbuf + base + 8192 + p);
    }
  };

  f32x4 acc[4][4] = {};
  stage(0, 0);
  const int nk = K / 32;
  for (int kt = 0; kt < nk; ++kt) {
    int buf = kt & 1;
    __syncthreads();
    if (kt + 1 < nk) stage(kt + 1, buf ^ 1);
    const char* Ab = ldsbuf + buf * 16384;
    const char* Bb = Ab + 8192;
    short8 af[4], bfr[4];
#pragma unroll
    for (int m = 0; m < 4; ++m)
      af[m] = *(const short8*)(Ab + (wm * 64 + m * 16 + (l & 15)) * 64 + g * 16);
#pragma unroll
    for (int n = 0; n < 4; ++n)
      bfr[n] = *(const short8*)(Bb + (wn * 64 + n * 16 + (l & 15)) * 64 + g * 16);
#pragma unroll
    for (int m = 0; m < 4; ++m)
#pragma unroll
      for (int n = 0; n < 4; ++n)
        acc[m][n] = __builtin_amdgcn_mfma_f32_16x16x32_bf16(af[m], bfr[n],
                                                            acc[m][n], 0, 0, 0);
    __syncthreads();
  }

  int row0 = bm * 128 + wm * 64;
  int col0 = bn * 128 + wn * 64;
  if (MODE == 2) {
    float* C = (float*)out;
#pragma unroll
    for (int m = 0; m < 4; ++m)
#pragma unroll
      for (int n = 0; n < 4; ++n)
#pragma unroll
        for (int r = 0; r < 4; ++r)
          C[(size_t)(row0 + m * 16 + g * 4 + r) * N + col0 + n * 16 + (l & 15)] =
              acc[m][n][r];
  } else if (MODE == 0) {
    unsigned short* C = (unsigned short*)out;
#pragma unroll
    for (int m = 0; m < 4; ++m)
#pragma unroll
      for (int n = 0; n < 2; ++n)
#pragma unroll
        for (int r = 0; r < 4; ++r) {
          int row = row0 + m * 16 + g * 4 + r;
          int t = row & (T_SEQ - 1);
          int d = n * 16 + (l & 15);  // 0..31
          float c = cosT[t * 32 + d], s = sinT[t * 32 + d];
          float v0 = acc[m][n][r], v1 = acc[m][n + 2][r];
          C[(size_t)row * N + col0 + d] = f2bf((v0 * c - v1 * s) * qscale);
          C[(size_t)row * N + col0 + d + 32] = f2bf((v1 * c + v0 * s) * qscale);
        }
  } else {  // MODE 1: V^T[b][e][t]
    unsigned short* C = (unsigned short*)out;
#pragma unroll
    for (int m = 0; m < 4; ++m) {
      int rowb = row0 + m * 16 + g * 4;
      int bb = rowb >> 11, t0 = rowb & (T_SEQ - 1);
#pragma unroll
      for (int n = 0; n < 4; ++n) {
        int e = col0 + n * 16 + (l & 15);
        unsigned long long pv =
            (unsigned long long)f2bf(acc[m][n][0]) |
            ((unsigned long long)f2bf(acc[m][n][1]) << 16) |
            ((unsigned long long)f2bf(acc[m][n][2]) << 32) |
            ((unsigned long long)f2bf(acc[m][n][3]) << 48);
        *(unsigned long long*)(C + ((size_t)bb * 1024 + e) * T_SEQ + t0) = pv;
      }
    }
  }
}

// ---------------- flash attention, swapped QK^T ----------------
__global__ __launch_bounds__(256, 2) void attn_kernel(
    const unsigned short* Qbf, const unsigned short* Kbf,
    const unsigned short* VT, unsigned short* attn_out) {
  int bid = blockIdx.x;
  int qb = bid >> 5;
  int bh = bid & 31;
  int b = bh >> 4, h = bh & 15;
  int tid = threadIdx.x;
  int l = tid & 63, w = tid >> 6;
  int g = l >> 4;
  int q0 = qb * 64;
  int qw = q0 + w * 16;

  __shared__ __align__(16) char kvbuf[2][2][8192];  // [buf][K|V][..]

  // Q B-fragments (scale folded in at GEMM): q row = qw + (l&15)
  short8 qf[2];
  {
    const char* qbase = (const char*)Qbf +
        ((size_t)(b * T_SEQ + qw + (l & 15)) * 1024 + h * 64) * 2 + g * 16;
    qf[0] = *(const short8*)qbase;
    qf[1] = *(const short8*)(qbase + 64);
  }

  auto stage = [&](int kt, int buf) {
#pragma unroll
    for (int i = 0; i < 2; ++i) {
      int p = (w * 2 + i) * 1024;
      int row = (p >> 7) + (l >> 3);
      int su = (l & 7) ^ (row & 7);  // pre-swizzled global source (rule #21)
      const char* gk = (const char*)Kbf +
          ((size_t)(b * T_SEQ + kt * 64 + row) * 1024 + h * 64) * 2 + su * 16;
      gld_lds16(gk, &kvbuf[buf][0][p]);
      const char* gv = (const char*)VT +
          ((size_t)(b * 1024 + h * 64 + row) * T_SEQ + (size_t)kt * 64) * 2 +
          su * 16;
      gld_lds16(gv, &kvbuf[buf][1][p]);
    }
  };

  f32x4 o[4] = {};
  float m_run = -1e30f, l_run = 0.f;
  stage(0, 0);
  int nt = qb + 1;
  for (int kt = 0; kt < nt; ++kt) {
    int buf = kt & 1;
    __syncthreads();
    if (kt + 1 < nt) stage(kt + 1, buf ^ 1);
    const char* Kl = kvbuf[buf][0];
    const char* Vl = kvbuf[buf][1];

    // S^T = K . Q^T  (4 kk-row frags x 16 q-cols)
    f32x4 st[4] = {};
#pragma unroll
    for (int ks = 0; ks < 2; ++ks)
#pragma unroll
      for (int f = 0; f < 4; ++f) {
        int row = f * 16 + (l & 15);
        int un = (g + 4 * ks) ^ (row & 7);
        short8 kf = *(const short8*)(Kl + row * 128 + un * 16);
        st[f] = __builtin_amdgcn_mfma_f32_16x16x32_bf16(kf, qf[ks], st[f], 0, 0, 0);
      }

    if (kt == qb) {  // causal mask on diagonal tile
      int qg = qw + (l & 15);
#pragma unroll
      for (int f = 0; f < 4; ++f)
#pragma unroll
        for (int r = 0; r < 4; ++r) {
          int kk = kt * 64 + f * 16 + g * 4 + r;
          if (kk > qg) st[f][r] = -1e30f;
        }
    }

    // online softmax: q = l&15 is lane-local; reduce over g via xor 16/32
    float tm = -1e30f;
#pragma unroll
    for (int f = 0; f < 4; ++f)
#pragma unroll
      for (int r = 0; r < 4; ++r) tm = fmaxf(tm, st[f][r]);
    tm = fmaxf(tm, __shfl_xor(tm, 16));
    tm = fmaxf(tm, __shfl_xor(tm, 32));
    float m_new = fmaxf(m_run, tm);
    float factor = __expf(m_run - m_new);
    float pl[4][4];
    float ls = 0.f;
#pragma unroll
    for (int f = 0; f < 4; ++f)
#pragma unroll
      for (int r = 0; r < 4; ++r) {
        float pv = __expf(st[f][r] - m_new);
        pl[f][r] = pv;
        ls += pv;
      }
    ls += __shfl_xor(ls, 16);
    ls += __shfl_xor(ls, 32);
    l_run = l_run * factor + ls;
    m_run = m_new;

    // rescale O (O rows are q=g*4+r; factor lives at lane q)
#pragma unroll
    for (int r = 0; r < 4; ++r) {
      float fr = __shfl(factor, g * 4 + r, 64);
#pragma unroll
      for (int c = 0; c < 4; ++c) o[c][r] *= fr;
    }

    // P (S^T layout) -> A-frag layout via packed bf16 + shfl
    unsigned pk01[4], pk23[4];
#pragma unroll
    for (int f = 0; f < 4; ++f) {
      pk01[f] = (unsigned)f2bf(pl[f][0]) | ((unsigned)f2bf(pl[f][1]) << 16);
      pk23[f] = (unsigned)f2bf(pl[f][2]) | ((unsigned)f2bf(pl[f][3]) << 16);
    }
    int srcA = (l & 15) + 32 * (g & 1);
    int srcB = srcA + 16;
    int fsel = g >> 1;
    short8 pa[2];
#pragma unroll
    for (int ks = 0; ks < 2; ++ks) {
      unsigned a0 = __shfl(pk01[2 * ks], srcA, 64);
      unsigned a0b = __shfl(pk01[2 * ks + 1], srcA, 64);
      unsigned a1 = __shfl(pk23[2 * ks], srcA, 64);
      unsigned a1b = __shfl(pk23[2 * ks + 1], srcA, 64);
      unsigned b0 = __shfl(pk01[2 * ks], srcB, 64);
      unsigned b0b = __shfl(pk01[2 * ks + 1], srcB, 64);
      unsigned b1 = __shfl(pk23[2 * ks], srcB, 64);
      unsigned b1b = __shfl(pk23[2 * ks + 1], srcB, 64);
      union {
        unsigned u[4];
        short8 s8;
      } uu;
      uu.u[0] = fsel ? a0b : a0;
      uu.u[1] = fsel ? a1b : a1;
      uu.u[2] = fsel ? b0b : b0;
      uu.u[3] = fsel ? b1b : b1;
      pa[ks] = uu.s8;
    }

    // O += P . V  (V^T rows = d in LDS)
#pragma unroll
    for (int ks = 0; ks < 2; ++ks)
#pragma unroll
      for (int c = 0; c < 4; ++c) {
        int row = c * 16 + (l & 15);
        int un = (g + 4 * ks) ^ (row & 7);
        short8 vf = *(const short8*)(Vl + row * 128 + un * 16);
        o[c] = __builtin_amdgcn_mfma_f32_16x16x32_bf16(pa[ks], vf, o[c], 0, 0, 0);
      }
    __syncthreads();
  }

  float linv[4];
#pragma unroll
  for (int r = 0; r < 4; ++r) {
    float lr = __shfl(l_run, g * 4 + r, 64);
    linv[r] = 1.0f / lr;
  }
#pragma unroll
  for (int c = 0; c < 4; ++c)
#pragma unroll
    for (int r = 0; r < 4; ++r) {
      int qg = qw + g * 4 + r;
      int col = h * 64 + c * 16 + (l & 15);
      attn_out[(size_t)(b * T_SEQ + qg) * 1024 + col] = f2bf(o[c][r] * linv[r]);
    }
}

extern "C" void kernel_launch(void* const* d_in, const int* in_sizes, int n_in,
                              void* d_out, int out_size, void* d_ws,
                              size_t ws_size, hipStream_t stream) {
  const float* x = (const float*)d_in[0];
  const float* Wq = (const float*)d_in[1];
  const float* Wk = (const float*)d_in[2];
  const float* Wv = (const float*)d_in[3];
  const float* Wo = (const float*)d_in[4];
  char* ws = (char*)d_ws;

  unsigned short* xb = (unsigned short*)(ws + OFF_XBF);
  unsigned short* wqb = (unsigned short*)(ws + OFF_WQ);
  unsigned short* wkb = (unsigned short*)(ws + OFF_WK);
  unsigned short* wvb = (unsigned short*)(ws + OFF_WV);
  unsigned short* wob = (unsigned short*)(ws + OFF_WO);
  unsigned short* qbf = (unsigned short*)(ws + OFF_Q);
  unsigned short* kbf = (unsigned short*)(ws + OFF_K);
  unsigned short* vtb = (unsigned short*)(ws + OFF_VT);
  unsigned short* att = (unsigned short*)(ws + OFF_ATT);
  const float* cosT = (const float*)(ws + OFF_COS);
  const float* sinT = (const float*)(ws + OFF_SIN);

  prep_kernel<<<2048, 256, 0, stream>>>(x, Wq, Wk, Wv, Wo, ws);
  gemm_bt<0><<<256, 256, 0, stream>>>(xb, wqb, qbf, cosT, sinT, 0.125f);
  gemm_bt<0><<<256, 256, 0, stream>>>(xb, wkb, kbf, cosT, sinT, 1.0f);
  gemm_bt<1><<<256, 256, 0, stream>>>(xb, wvb, vtb, nullptr, nullptr, 1.0f);
  attn_kernel<<<1024, 256, 0, stream>>>(qbf, kbf, vtb, att);
  gemm_bt<2><<<256, 256, 0, stream>>>(att, wob, d_out, nullptr, nullptr, 1.0f);
}